// Round 5
// baseline (156.602 us; speedup 1.0000x reference)
//
#include <hip/hip_runtime.h>
#include <hip/hip_bf16.h>

// MMD-RBF: B=4, Ns=Nt=2048 (N=4096 concat), K=32, KERNEL_MUL=2, KERNEL_NUM=5.
// Pass 1: per-point sq-norms + per-block partial {sum_sq, component sums} (no atomics)
// Pass 2: reduce partials -> bandwidth coefficients; zero quadbuf (no memset node)
// Pass 3: upper-tri 128x128 tile pairs (bx<=by), block=128 thr (2 waves);
//         rows pinned in VGPRs, columns via block-uniform scalar loads;
//         geometric-bandwidth exp chain: e_{t-1} = e_t^2 (1 exp2 per pair);
//         off-diag tiles counted into both (q,qT) quadrants (kernel symmetry)
// Pass 4: out[b] = (XX + YY - XY - YX) / 2048^2

#define NPTS 4096   // per batch (2048 src + 2048 tgt)
#define HALF 2048
#define KDIM 32
#define T3   128    // pass3 tile dim
#define NTB3 32     // NPTS / T3
#define SPREAD 64

__device__ __forceinline__ float fast_exp2(float x) {
#if __has_builtin(__builtin_amdgcn_exp2f)
  return __builtin_amdgcn_exp2f(x);
#else
  return exp2f(x);
#endif
}

__device__ __forceinline__ const float* point_ptr(const float* __restrict__ src,
                                                  const float* __restrict__ tgt,
                                                  int b, int p) {
  return (p < HALF) ? src + ((size_t)b * HALF + p) * KDIM
                    : tgt + ((size_t)b * HALF + (p - HALF)) * KDIM;
}

// ---- Pass 1: sq per point; per-block partial {sum_sq, comp sums} -> part1 --
__global__ void mmd_pass1(const float* __restrict__ src, const float* __restrict__ tgt,
                          float* __restrict__ sqArr, double* __restrict__ part1) {
  const int b = blockIdx.y;
  const int p = blockIdx.x * 256 + threadIdx.x;
  const float* __restrict__ xp = point_ptr(src, tgt, b, p);

  float x[KDIM];
#pragma unroll
  for (int q = 0; q < 8; ++q) {
    float4 v = reinterpret_cast<const float4*>(xp)[q];
    x[4*q+0] = v.x; x[4*q+1] = v.y; x[4*q+2] = v.z; x[4*q+3] = v.w;
  }
  float s0 = 0.f, s1 = 0.f, s2 = 0.f, s3 = 0.f;
#pragma unroll
  for (int q = 0; q < 8; ++q) {
    s0 = fmaf(x[4*q+0], x[4*q+0], s0);
    s1 = fmaf(x[4*q+1], x[4*q+1], s1);
    s2 = fmaf(x[4*q+2], x[4*q+2], s2);
    s3 = fmaf(x[4*q+3], x[4*q+3], s3);
  }
  float sq = (s0 + s1) + (s2 + s3);
  sqArr[(size_t)b * NPTS + p] = sq;

  __shared__ float lx[256][KDIM + 1];   // +1 pad: column reads conflict-free
  __shared__ float part[8][KDIM];
  __shared__ float sqpart[4];

#pragma unroll
  for (int k = 0; k < KDIM; ++k) lx[threadIdx.x][k] = x[k];

  float w = sq;
#pragma unroll
  for (int off = 32; off > 0; off >>= 1) w += __shfl_down(w, off, 64);
  if ((threadIdx.x & 63) == 0) sqpart[threadIdx.x >> 6] = w;
  __syncthreads();

  const int k = threadIdx.x & 31, g = threadIdx.x >> 5;
  float ps = 0.f;
#pragma unroll 8
  for (int r = 0; r < 32; ++r) ps += lx[g * 32 + r][k];
  part[g][k] = ps;
  __syncthreads();

  double* slot = part1 + ((size_t)b * 16 + blockIdx.x) * 33;
  if (threadIdx.x < 32) {
    float tot = 0.f;
#pragma unroll
    for (int gg = 0; gg < 8; ++gg) tot += part[gg][threadIdx.x];
    slot[1 + threadIdx.x] = (double)tot;
  }
  if (threadIdx.x == 63) {
    slot[0] = (double)(sqpart[0] + sqpart[1] + sqpart[2] + sqpart[3]);
  }
}

// ---- Pass 2: reduce partials -> coef; zero quadbuf -------------------------
__global__ void mmd_pass2(const double* __restrict__ part1, float* __restrict__ coef,
                          double* __restrict__ quadbuf) {
  const int tid = threadIdx.x;  // 256
  for (int i = tid; i < 4 * 4 * SPREAD; i += 256) quadbuf[i] = 0.0;

  __shared__ double sv[4][KDIM];
  if (tid < 128) {
    const int b = tid >> 5, k = tid & 31;
    double s = 0.0;
    for (int blk = 0; blk < 16; ++blk) s += part1[((size_t)b * 16 + blk) * 33 + 1 + k];
    sv[b][k] = s;
  }
  __syncthreads();
  if (tid < 4) {
    const int b = tid;
    double ssq = 0.0;
    for (int blk = 0; blk < 16; ++blk) ssq += part1[((size_t)b * 16 + blk) * 33];
    double s2 = 0.0;
    for (int k = 0; k < KDIM; ++k) s2 += sv[b][k] * sv[b][k];
    const double N = (double)NPTS;
    double sumL2 = 2.0 * N * ssq - 2.0 * s2;
    double bw = sumL2 / (N * N - N + 1e-8);
    bw *= 0.25;  // / KERNEL_MUL^(KERNEL_NUM/2) = / 4
    const double LOG2E = 1.4426950408889634;
    // only the widest-bandwidth coefficient is needed (t=4); chain squares the rest
    coef[b] = (float)(-LOG2E / (bw * 16.0));
  }
}

// ---- Pass 3: upper-tri 128x128 tile pairs, symmetry-doubled ----------------
__global__ void __launch_bounds__(128, 4)
mmd_pass3(const float* __restrict__ src, const float* __restrict__ tgt,
          const float* __restrict__ sqArr, const float* __restrict__ coef,
          double* __restrict__ quadbuf) {
  const int bx = blockIdx.x;
  const int by = blockIdx.y;
  if (bx > by) return;                 // upper triangle only (symmetry)
  const int b = blockIdx.z;

  const int tid = threadIdx.x;         // 0..127, one row each
  const int row = bx * T3 + tid;
  const int col0 = by * T3;            // block-uniform -> scalar col loads

  const float* __restrict__ rp = point_ptr(src, tgt, b, row);
  float r[KDIM];
#pragma unroll
  for (int q = 0; q < 8; ++q) {
    float4 v = reinterpret_cast<const float4*>(rp)[q];
    r[4*q+0] = v.x; r[4*q+1] = v.y; r[4*q+2] = v.z; r[4*q+3] = v.w;
  }
  // Pin the row in VGPRs: opaque def the loads can't be sunk past / remat'd.
#pragma unroll
  for (int k = 0; k < KDIM; ++k) asm volatile("" : "+v"(r[k]));

  const float sq_i = sqArr[(size_t)b * NPTS + row];
  const float nc4 = coef[b];           // -log2(e)/(bw*16)

  const float* __restrict__ cbase = point_ptr(src, tgt, b, col0);
  const float* __restrict__ sqc = sqArr + (size_t)b * NPTS + col0;

  double acc = 0.0;
  for (int jc = 0; jc < T3 / 8; ++jc) {
    float partf = 0.f;
#pragma unroll 2
    for (int jj = 0; jj < 8; ++jj) {
      const int j = jc * 8 + jj;
      const float4* __restrict__ cp4 =
          reinterpret_cast<const float4*>(cbase + (size_t)j * KDIM);
      const float sq_j = sqc[j];
      float d0 = 0.f, d1 = 0.f, d2 = 0.f, d3 = 0.f;
#pragma unroll
      for (int q = 0; q < 8; ++q) {
        float4 cv = cp4[q];
        d0 = fmaf(r[4*q+0], cv.x, d0);
        d1 = fmaf(r[4*q+1], cv.y, d1);
        d2 = fmaf(r[4*q+2], cv.z, d2);
        d3 = fmaf(r[4*q+3], cv.w, d3);
      }
      const float dot = (d0 + d1) + (d2 + d3);
      const float L2 = fmaf(-2.0f, dot, sq_i + sq_j);
      // geometric bandwidth ladder: e_t = exp(-L2/(bw*2^t)); e_{t-1} = e_t^2
      const float e4 = fast_exp2(L2 * nc4);
      const float e3 = e4 * e4;
      const float e2 = e3 * e3;
      const float e1 = e2 * e2;
      const float e0 = e1 * e1;
      partf += ((e4 + e3) + (e2 + e1)) + e0;
    }
    acc += (double)partf;
  }

  // reduce: wave (f64 shuffle) then 2-wave combine in LDS
#pragma unroll
  for (int off = 32; off > 0; off >>= 1) acc += __shfl_down(acc, off, 64);
  __shared__ double wsum[2];
  if ((tid & 63) == 0) wsum[tid >> 6] = acc;
  __syncthreads();
  if (tid == 0) {
    const double tot = wsum[0] + wsum[1];
    const int rh = (bx >= NTB3 / 2) ? 1 : 0;   // row half (0=X, 1=Y)
    const int ch = (by >= NTB3 / 2) ? 1 : 0;   // col half
    const int q  = (rh << 1) | ch;
    const int qT = (ch << 1) | rh;
    const int slot = (bx + by * NTB3) & (SPREAD - 1);
    atomicAdd(&quadbuf[(((b << 2) | q) * SPREAD) + slot], tot);
    if (bx != by)
      atomicAdd(&quadbuf[(((b << 2) | qT) * SPREAD) + slot], tot);
  }
}

// ---- Pass 4: final combine -------------------------------------------------
__global__ void mmd_pass4(const double* __restrict__ quadbuf, float* __restrict__ out) {
  const int b = threadIdx.x;
  if (b < 4) {
    double q[4];
#pragma unroll
    for (int qq = 0; qq < 4; ++qq) {
      double s = 0.0;
      for (int i = 0; i < SPREAD; ++i) s += quadbuf[((b << 2) | qq) * SPREAD + i];
      q[qq] = s;
    }
    const double inv = 1.0 / ((double)HALF * (double)HALF);
    out[b] = (float)((q[0] + q[3] - q[1] - q[2]) * inv);
  }
}

extern "C" void kernel_launch(void* const* d_in, const int* in_sizes, int n_in,
                              void* d_out, int out_size, void* d_ws, size_t ws_size,
                              hipStream_t stream) {
  const float* src = (const float*)d_in[0];
  const float* tgt = (const float*)d_in[1];
  float* out = (float*)d_out;

  char* ws = (char*)d_ws;
  float*  sqArr   = (float*)ws;                  // 4*4096*4           = 65536 B
  double* part1   = (double*)(ws + 65536);       // 4*16*33*8          = 16896 B
  double* quadbuf = (double*)(ws + 82432);       // 4*4*64*8           = 8192 B
  float*  coef    = (float*)(ws + 90624);        // 4*4                = 16 B

  mmd_pass1<<<dim3(NPTS / 256, 4), 256, 0, stream>>>(src, tgt, sqArr, part1);
  mmd_pass2<<<1, 256, 0, stream>>>(part1, coef, quadbuf);
  mmd_pass3<<<dim3(NTB3, NTB3, 4), 128, 0, stream>>>(src, tgt, sqArr, coef, quadbuf);
  mmd_pass4<<<1, 64, 0, stream>>>(quadbuf, out);
}

// Round 6
// 124.230 us; speedup vs baseline: 1.2606x; 1.2606x over previous
//
#include <hip/hip_runtime.h>
#include <hip/hip_bf16.h>

// MMD-RBF: B=4, Ns=Nt=2048 (N=4096 concat), K=32, KERNEL_MUL=2, KERNEL_NUM=5.
// Pass 1: per-point sq-norms + per-block partial {sum_sq, comp sums}; zero quadbuf
// Pass 3: upper-tri 128x128 tile pairs (bx<=by), 256 thr, LDS-staged tiles,
//         8x8 register outer-product per thread, per-block coef recompute,
//         geometric-bandwidth exp chain e_{t-1}=e_t^2 (1 exp2/pair),
//         off-diag tiles counted into both (q,qT) quadrants (kernel symmetry)
// Pass 4: out[b] = (XX + YY - XY - YX) / 2048^2

#define NPTS 4096   // per batch (2048 src + 2048 tgt)
#define HALF 2048
#define KDIM 32
#define T3   128    // pass3 tile dim
#define NTB3 32     // NPTS / T3
#define SPREAD 64

__device__ __forceinline__ float fast_exp2(float x) {
#if __has_builtin(__builtin_amdgcn_exp2f)
  return __builtin_amdgcn_exp2f(x);
#else
  return exp2f(x);
#endif
}

__device__ __forceinline__ const float* point_ptr(const float* __restrict__ src,
                                                  const float* __restrict__ tgt,
                                                  int b, int p) {
  return (p < HALF) ? src + ((size_t)b * HALF + p) * KDIM
                    : tgt + ((size_t)b * HALF + (p - HALF)) * KDIM;
}

// ---- Pass 1: sq per point; per-block partials -> part1; zero quadbuf -------
__global__ void mmd_pass1(const float* __restrict__ src, const float* __restrict__ tgt,
                          float* __restrict__ sqArr, double* __restrict__ part1,
                          double* __restrict__ quadbuf) {
  const int b = blockIdx.y;
  const int p = blockIdx.x * 256 + threadIdx.x;

  if (blockIdx.x == 0)  // zero this batch's 256 quadbuf slots (before pass3)
    quadbuf[b * 4 * SPREAD + threadIdx.x] = 0.0;

  const float* __restrict__ xp = point_ptr(src, tgt, b, p);
  float x[KDIM];
#pragma unroll
  for (int q = 0; q < 8; ++q) {
    float4 v = reinterpret_cast<const float4*>(xp)[q];
    x[4*q+0] = v.x; x[4*q+1] = v.y; x[4*q+2] = v.z; x[4*q+3] = v.w;
  }
  float s0 = 0.f, s1 = 0.f, s2 = 0.f, s3 = 0.f;
#pragma unroll
  for (int q = 0; q < 8; ++q) {
    s0 = fmaf(x[4*q+0], x[4*q+0], s0);
    s1 = fmaf(x[4*q+1], x[4*q+1], s1);
    s2 = fmaf(x[4*q+2], x[4*q+2], s2);
    s3 = fmaf(x[4*q+3], x[4*q+3], s3);
  }
  float sq = (s0 + s1) + (s2 + s3);
  sqArr[(size_t)b * NPTS + p] = sq;

  __shared__ float lx[256][KDIM + 1];
  __shared__ float part[8][KDIM];
  __shared__ float sqpart[4];

#pragma unroll
  for (int k = 0; k < KDIM; ++k) lx[threadIdx.x][k] = x[k];

  float w = sq;
#pragma unroll
  for (int off = 32; off > 0; off >>= 1) w += __shfl_down(w, off, 64);
  if ((threadIdx.x & 63) == 0) sqpart[threadIdx.x >> 6] = w;
  __syncthreads();

  const int k = threadIdx.x & 31, g = threadIdx.x >> 5;
  float ps = 0.f;
#pragma unroll 8
  for (int r = 0; r < 32; ++r) ps += lx[g * 32 + r][k];
  part[g][k] = ps;
  __syncthreads();

  double* slot = part1 + ((size_t)b * 16 + blockIdx.x) * 33;
  if (threadIdx.x < 32) {
    float tot = 0.f;
#pragma unroll
    for (int gg = 0; gg < 8; ++gg) tot += part[gg][threadIdx.x];
    slot[1 + threadIdx.x] = (double)tot;
  }
  if (threadIdx.x == 63)
    slot[0] = (double)(sqpart[0] + sqpart[1] + sqpart[2] + sqpart[3]);
}

// ---- Pass 3: LDS-tiled 128x128 GEMM-with-epilogue, upper-tri, sym-doubled --
// LDS tile layout (per k): word = k*128 + ((pt&4)?64:0) + (pt>>3)*4 + (pt&3)
// -> frag reads are 2x ds_read_b128 at words k*128+{0,64}+t*4 (<=2-way banks)
__global__ void __launch_bounds__(256, 2)
mmd_pass3(const float* __restrict__ src, const float* __restrict__ tgt,
          const float* __restrict__ sqArr, const double* __restrict__ part1,
          double* __restrict__ quadbuf) {
  const int bx = blockIdx.x;
  const int by = blockIdx.y;
  if (bx > by) return;                 // upper triangle only (symmetry)
  const int b = blockIdx.z;
  const int tid = threadIdx.x;         // 256
  const int tx = tid & 15, ty = tid >> 4;

  __shared__ __align__(16) float As[32 * 128];
  __shared__ __align__(16) float Bs[32 * 128];
  __shared__ float s_sqA[128], s_sqB[128];
  __shared__ double red[33];
  __shared__ float s_nc4;
  __shared__ double wsum[4];

  // per-block bandwidth partial reduce (deterministic, identical across blocks)
  if (tid < 33) {
    double s = 0.0;
    for (int blk = 0; blk < 16; ++blk) s += part1[((size_t)b * 16 + blk) * 33 + tid];
    red[tid] = s;
  }

  // stage A (rows: bx tile) and B (cols: by tile) into LDS, interleaved layout
  {
    const int p = tid >> 1, h = tid & 1;
    const int cw = ((p & 4) << 4) + ((p >> 3) << 2) + (p & 3);
    const float* __restrict__ ra = point_ptr(src, tgt, b, bx * T3 + p);
    const float* __restrict__ rb = point_ptr(src, tgt, b, by * T3 + p);
    const float4* ra4 = reinterpret_cast<const float4*>(ra);
    const float4* rb4 = reinterpret_cast<const float4*>(rb);
#pragma unroll
    for (int qi = 0; qi < 4; ++qi) {
      float4 va = ra4[h * 4 + qi];
      float4 vb = rb4[h * 4 + qi];
      const int k0 = h * 16 + qi * 4;
      As[(k0+0)*128 + cw] = va.x;  As[(k0+1)*128 + cw] = va.y;
      As[(k0+2)*128 + cw] = va.z;  As[(k0+3)*128 + cw] = va.w;
      Bs[(k0+0)*128 + cw] = vb.x;  Bs[(k0+1)*128 + cw] = vb.y;
      Bs[(k0+2)*128 + cw] = vb.z;  Bs[(k0+3)*128 + cw] = vb.w;
    }
    if (tid < 128) s_sqA[tid] = sqArr[(size_t)b * NPTS + bx * T3 + tid];
    else           s_sqB[tid - 128] = sqArr[(size_t)b * NPTS + by * T3 + (tid - 128)];
  }
  __syncthreads();

  if (tid == 0) {
    double ssq = red[0], s2 = 0.0;
    for (int k = 1; k <= 32; ++k) s2 += red[k] * red[k];
    const double N = (double)NPTS;
    double bw = (2.0 * N * ssq - 2.0 * s2) / (N * N - N + 1e-8);
    bw *= 0.25;  // / KERNEL_MUL^(KERNEL_NUM//2)
    s_nc4 = (float)(-1.4426950408889634 / (bw * 16.0));  // widest bandwidth (t=4)
  }
  __syncthreads();

  // 8x8 register outer-product over K=32
  float acc[8][8] = {};
  const int ao = ty << 2, bo = tx << 2;
#pragma unroll 4
  for (int k = 0; k < 32; ++k) {
    const float4 alo = *reinterpret_cast<const float4*>(&As[k*128 + ao]);
    const float4 ahi = *reinterpret_cast<const float4*>(&As[k*128 + 64 + ao]);
    const float4 blo = *reinterpret_cast<const float4*>(&Bs[k*128 + bo]);
    const float4 bhi = *reinterpret_cast<const float4*>(&Bs[k*128 + 64 + bo]);
    const float a[8] = {alo.x, alo.y, alo.z, alo.w, ahi.x, ahi.y, ahi.z, ahi.w};
    const float bb[8] = {blo.x, blo.y, blo.z, blo.w, bhi.x, bhi.y, bhi.z, bhi.w};
#pragma unroll
    for (int i = 0; i < 8; ++i)
#pragma unroll
      for (int j = 0; j < 8; ++j)
        acc[i][j] = fmaf(a[i], bb[j], acc[i][j]);
  }

  // fused epilogue: L2 -> geometric exp ladder -> f64 accumulate
  const float nc4 = s_nc4;
  double accd = 0.0;
#pragma unroll
  for (int i = 0; i < 8; ++i) {
    const float sqi = s_sqA[ty * 8 + i];
    float rowsum = 0.f;
#pragma unroll
    for (int j = 0; j < 8; ++j) {
      const float L2 = fmaf(-2.0f, acc[i][j], sqi + s_sqB[tx * 8 + j]);
      const float e4 = fast_exp2(L2 * nc4);
      const float e3 = e4 * e4;
      const float e2 = e3 * e3;
      const float e1 = e2 * e2;
      const float e0 = e1 * e1;
      rowsum += ((e4 + e3) + (e2 + e1)) + e0;
    }
    accd += (double)rowsum;
  }

  // block reduce (4 waves) + spread atomics
#pragma unroll
  for (int off = 32; off > 0; off >>= 1) accd += __shfl_down(accd, off, 64);
  if ((tid & 63) == 0) wsum[tid >> 6] = accd;
  __syncthreads();
  if (tid == 0) {
    const double tot = wsum[0] + wsum[1] + wsum[2] + wsum[3];
    const int rh = (bx >= NTB3 / 2) ? 1 : 0;
    const int ch = (by >= NTB3 / 2) ? 1 : 0;
    const int q  = (rh << 1) | ch;
    const int qT = (ch << 1) | rh;
    const int slot = (bx + by * NTB3) & (SPREAD - 1);
    atomicAdd(&quadbuf[(((b << 2) | q) * SPREAD) + slot], tot);
    if (bx != by)
      atomicAdd(&quadbuf[(((b << 2) | qT) * SPREAD) + slot], tot);
  }
}

// ---- Pass 4: final combine -------------------------------------------------
__global__ void mmd_pass4(const double* __restrict__ quadbuf, float* __restrict__ out) {
  const int b = threadIdx.x;
  if (b < 4) {
    double q[4];
#pragma unroll
    for (int qq = 0; qq < 4; ++qq) {
      double s = 0.0;
      for (int i = 0; i < SPREAD; ++i) s += quadbuf[((b << 2) | qq) * SPREAD + i];
      q[qq] = s;
    }
    const double inv = 1.0 / ((double)HALF * (double)HALF);
    out[b] = (float)((q[0] + q[3] - q[1] - q[2]) * inv);
  }
}

extern "C" void kernel_launch(void* const* d_in, const int* in_sizes, int n_in,
                              void* d_out, int out_size, void* d_ws, size_t ws_size,
                              hipStream_t stream) {
  const float* src = (const float*)d_in[0];
  const float* tgt = (const float*)d_in[1];
  float* out = (float*)d_out;

  char* ws = (char*)d_ws;
  float*  sqArr   = (float*)ws;                  // 4*4096*4  = 65536 B
  double* part1   = (double*)(ws + 65536);       // 4*16*33*8 = 16896 B
  double* quadbuf = (double*)(ws + 82432);       // 4*4*64*8  = 8192 B

  mmd_pass1<<<dim3(NPTS / 256, 4), 256, 0, stream>>>(src, tgt, sqArr, part1, quadbuf);
  mmd_pass3<<<dim3(NTB3, NTB3, 4), 256, 0, stream>>>(src, tgt, sqArr, part1, quadbuf);
  mmd_pass4<<<1, 64, 0, stream>>>(quadbuf, out);
}

// Round 7
// 121.181 us; speedup vs baseline: 1.2923x; 1.0252x over previous
//
#include <hip/hip_runtime.h>
#include <hip/hip_bf16.h>

// MMD-RBF: B=4, Ns=Nt=2048 (N=4096 concat), K=32, KERNEL_MUL=2, KERNEL_NUM=5.
// Pass 1: per-point sq-norms + per-block partial {sum_sq, comp sums}; zero quadbuf+cnt
// Pass 3: 528 upper-tri 128x128 tile pairs per batch (1D grid, no dead blocks),
//         LDS-staged tiles, 8x8 register outer-product, explicit k+1 prefetch,
//         geometric-bandwidth exp chain e_{t-1}=e_t^2 (1 exp2/pair),
//         off-diag tiles counted into both (q,qT) quadrants (kernel symmetry),
//         completion-counter: last block per batch combines quadrants -> out[b]

#define NPTS 4096   // per batch (2048 src + 2048 tgt)
#define HALF 2048
#define KDIM 32
#define T3   128    // pass3 tile dim
#define NTB3 32     // NPTS / T3
#define NPAIR3 528  // NTB3*(NTB3+1)/2
#define SPREAD 64

__device__ __forceinline__ float fast_exp2(float x) {
#if __has_builtin(__builtin_amdgcn_exp2f)
  return __builtin_amdgcn_exp2f(x);
#else
  return exp2f(x);
#endif
}

__device__ __forceinline__ const float* point_ptr(const float* __restrict__ src,
                                                  const float* __restrict__ tgt,
                                                  int b, int p) {
  return (p < HALF) ? src + ((size_t)b * HALF + p) * KDIM
                    : tgt + ((size_t)b * HALF + (p - HALF)) * KDIM;
}

// ---- Pass 1: sq per point; per-block partials -> part1; zero quadbuf+cnt ---
__global__ void mmd_pass1(const float* __restrict__ src, const float* __restrict__ tgt,
                          float* __restrict__ sqArr, double* __restrict__ part1,
                          double* __restrict__ quadbuf, unsigned int* __restrict__ cnt) {
  const int b = blockIdx.y;
  const int p = blockIdx.x * 256 + threadIdx.x;

  if (blockIdx.x == 0) {  // zero this batch's 256 quadbuf slots + counter
    quadbuf[b * 4 * SPREAD + threadIdx.x] = 0.0;
    if (threadIdx.x == 0) cnt[b] = 0u;
  }

  const float* __restrict__ xp = point_ptr(src, tgt, b, p);
  float x[KDIM];
#pragma unroll
  for (int q = 0; q < 8; ++q) {
    float4 v = reinterpret_cast<const float4*>(xp)[q];
    x[4*q+0] = v.x; x[4*q+1] = v.y; x[4*q+2] = v.z; x[4*q+3] = v.w;
  }
  float s0 = 0.f, s1 = 0.f, s2 = 0.f, s3 = 0.f;
#pragma unroll
  for (int q = 0; q < 8; ++q) {
    s0 = fmaf(x[4*q+0], x[4*q+0], s0);
    s1 = fmaf(x[4*q+1], x[4*q+1], s1);
    s2 = fmaf(x[4*q+2], x[4*q+2], s2);
    s3 = fmaf(x[4*q+3], x[4*q+3], s3);
  }
  float sq = (s0 + s1) + (s2 + s3);
  sqArr[(size_t)b * NPTS + p] = sq;

  __shared__ float lx[256][KDIM + 1];
  __shared__ float part[8][KDIM];
  __shared__ float sqpart[4];

#pragma unroll
  for (int k = 0; k < KDIM; ++k) lx[threadIdx.x][k] = x[k];

  float w = sq;
#pragma unroll
  for (int off = 32; off > 0; off >>= 1) w += __shfl_down(w, off, 64);
  if ((threadIdx.x & 63) == 0) sqpart[threadIdx.x >> 6] = w;
  __syncthreads();

  const int k = threadIdx.x & 31, g = threadIdx.x >> 5;
  float ps = 0.f;
#pragma unroll 8
  for (int r = 0; r < 32; ++r) ps += lx[g * 32 + r][k];
  part[g][k] = ps;
  __syncthreads();

  double* slot = part1 + ((size_t)b * 16 + blockIdx.x) * 33;
  if (threadIdx.x < 32) {
    float tot = 0.f;
#pragma unroll
    for (int gg = 0; gg < 8; ++gg) tot += part[gg][threadIdx.x];
    slot[1 + threadIdx.x] = (double)tot;
  }
  if (threadIdx.x == 63)
    slot[0] = (double)(sqpart[0] + sqpart[1] + sqpart[2] + sqpart[3]);
}

// ---- Pass 3: LDS-tiled 128x128 GEMM + epilogue, upper-tri, sym-doubled -----
// LDS layout (per k-row of 128 words): word cw(p) = ((p&4)<<4)+((p>>3)<<2)+(p&3)
// -> frag reads are ds_read_b128 at float4-index k*32 + {ty, 16+ty, tx, 16+tx}
__global__ void __launch_bounds__(256, 4)
mmd_pass3(const float* __restrict__ src, const float* __restrict__ tgt,
          const float* __restrict__ sqArr, const double* __restrict__ part1,
          double* __restrict__ quadbuf, unsigned int* __restrict__ cnt,
          float* __restrict__ out) {
  const int t = blockIdx.x;            // 0..527 upper-tri pair index
  const int b = blockIdx.y;
  // decode: by = largest with by*(by+1)/2 <= t ; bx = t - cum(by); bx <= by
  int by = (int)((sqrtf((float)(8 * t + 1)) - 1.0f) * 0.5f);
  while ((by + 1) * (by + 2) / 2 <= t) ++by;
  while (by * (by + 1) / 2 > t) --by;
  const int bx = t - by * (by + 1) / 2;

  const int tid = threadIdx.x;         // 256
  const int tx = tid & 15, ty = tid >> 4;

  __shared__ __align__(16) float As[32 * 128];
  __shared__ __align__(16) float Bs[32 * 128];
  __shared__ float s_sqA[128], s_sqB[128];
  __shared__ double red[33];
  __shared__ float s_nc4;
  __shared__ double wsum[4];
  __shared__ unsigned int s_last;

  // per-block bandwidth partial reduce (deterministic, identical across blocks)
  if (tid < 33) {
    double s = 0.0;
    for (int blk = 0; blk < 16; ++blk) s += part1[((size_t)b * 16 + blk) * 33 + tid];
    red[tid] = s;
  }

  // stage A (bx tile) and B (by tile): thread = (point p, half h) -> banks 0..31
  {
    const int p = tid & 127, h = tid >> 7;
    const int cw = ((p & 4) << 4) + ((p >> 3) << 2) + (p & 3);
    const float* __restrict__ ra = point_ptr(src, tgt, b, bx * T3 + p);
    const float* __restrict__ rb = point_ptr(src, tgt, b, by * T3 + p);
    const float4* ra4 = reinterpret_cast<const float4*>(ra);
    const float4* rb4 = reinterpret_cast<const float4*>(rb);
#pragma unroll
    for (int qi = 0; qi < 4; ++qi) {
      float4 va = ra4[h * 4 + qi];
      float4 vb = rb4[h * 4 + qi];
      const int k0 = h * 16 + qi * 4;
      As[(k0+0)*128 + cw] = va.x;  As[(k0+1)*128 + cw] = va.y;
      As[(k0+2)*128 + cw] = va.z;  As[(k0+3)*128 + cw] = va.w;
      Bs[(k0+0)*128 + cw] = vb.x;  Bs[(k0+1)*128 + cw] = vb.y;
      Bs[(k0+2)*128 + cw] = vb.z;  Bs[(k0+3)*128 + cw] = vb.w;
    }
    if (tid < 128) s_sqA[tid] = sqArr[(size_t)b * NPTS + bx * T3 + tid];
    else           s_sqB[tid - 128] = sqArr[(size_t)b * NPTS + by * T3 + (tid - 128)];
  }
  __syncthreads();

  if (tid == 0) {
    double ssq = red[0], s2 = 0.0;
    for (int k = 1; k <= 32; ++k) s2 += red[k] * red[k];
    const double N = (double)NPTS;
    double bw = (2.0 * N * ssq - 2.0 * s2) / (N * N - N + 1e-8);
    bw *= 0.25;  // / KERNEL_MUL^(KERNEL_NUM//2)
    s_nc4 = (float)(-1.4426950408889634 / (bw * 16.0));  // widest bandwidth (t=4)
  }
  __syncthreads();

  // 8x8 register outer-product over K=32, explicit k+1 prefetch
  const float4* As4 = reinterpret_cast<const float4*>(As);
  const float4* Bs4 = reinterpret_cast<const float4*>(Bs);
  float acc[8][8] = {};
  float4 ca0 = As4[ty], ca1 = As4[16 + ty];
  float4 cb0 = Bs4[tx], cb1 = Bs4[16 + tx];
#pragma unroll
  for (int k = 0; k < 32; ++k) {
    const int o = ((k + 1) & 31) * 32;   // k=31 wraps: harmless reload
    float4 na0 = As4[o + ty], na1 = As4[o + 16 + ty];
    float4 nb0 = Bs4[o + tx], nb1 = Bs4[o + 16 + tx];
    const float a[8]  = {ca0.x, ca0.y, ca0.z, ca0.w, ca1.x, ca1.y, ca1.z, ca1.w};
    const float bb[8] = {cb0.x, cb0.y, cb0.z, cb0.w, cb1.x, cb1.y, cb1.z, cb1.w};
#pragma unroll
    for (int i = 0; i < 8; ++i)
#pragma unroll
      for (int j = 0; j < 8; ++j)
        acc[i][j] = fmaf(a[i], bb[j], acc[i][j]);
    ca0 = na0; ca1 = na1; cb0 = nb0; cb1 = nb1;
  }

  // fused epilogue: L2 -> geometric exp ladder -> f64 accumulate
  const float nc4 = s_nc4;
  double accd = 0.0;
#pragma unroll
  for (int i = 0; i < 8; ++i) {
    const float sqi = s_sqA[ty * 8 + i];
    float rowsum = 0.f;
#pragma unroll
    for (int j = 0; j < 8; ++j) {
      const float L2 = fmaf(-2.0f, acc[i][j], sqi + s_sqB[tx * 8 + j]);
      const float e4 = fast_exp2(L2 * nc4);
      const float e3 = e4 * e4;
      const float e2 = e3 * e3;
      const float e1 = e2 * e2;
      const float e0 = e1 * e1;
      rowsum += ((e4 + e3) + (e2 + e1)) + e0;
    }
    accd += (double)rowsum;
  }

  // block reduce (4 waves) + spread atomics
#pragma unroll
  for (int off = 32; off > 0; off >>= 1) accd += __shfl_down(accd, off, 64);
  if ((tid & 63) == 0) wsum[tid >> 6] = accd;
  __syncthreads();
  if (tid == 0) {
    const double tot = wsum[0] + wsum[1] + wsum[2] + wsum[3];
    const int rh = (bx >= NTB3 / 2) ? 1 : 0;
    const int ch = (by >= NTB3 / 2) ? 1 : 0;
    const int q  = (rh << 1) | ch;
    const int qT = (ch << 1) | rh;
    const int slot = (bx + by * NTB3) & (SPREAD - 1);
    atomicAdd(&quadbuf[(((b << 2) | q) * SPREAD) + slot], tot);
    if (bx != by)
      atomicAdd(&quadbuf[(((b << 2) | qT) * SPREAD) + slot], tot);
    __threadfence();
    s_last = atomicAdd(&cnt[b], 1u);   // old count
  }
  __syncthreads();

  // last block of this batch combines the quadrants -> out[b]
  if (s_last == NPAIR3 - 1) {
    const int qq = tid >> 6, i = tid & 63;
    // atomic RMW (+0.0) readback: coherent with producers' device-scope atomics
    double v = atomicAdd(&quadbuf[((b << 2) | qq) * SPREAD + i], 0.0);
    double sv = (qq == 0 || qq == 3) ? v : -v;
#pragma unroll
    for (int off = 32; off > 0; off >>= 1) sv += __shfl_down(sv, off, 64);
    if ((tid & 63) == 0) wsum[tid >> 6] = sv;
    __syncthreads();
    if (tid == 0) {
      const double inv = 1.0 / ((double)HALF * (double)HALF);
      out[b] = (float)((wsum[0] + wsum[1] + wsum[2] + wsum[3]) * inv);
    }
  }
}

extern "C" void kernel_launch(void* const* d_in, const int* in_sizes, int n_in,
                              void* d_out, int out_size, void* d_ws, size_t ws_size,
                              hipStream_t stream) {
  const float* src = (const float*)d_in[0];
  const float* tgt = (const float*)d_in[1];
  float* out = (float*)d_out;

  char* ws = (char*)d_ws;
  float*        sqArr   = (float*)ws;             // 4*4096*4  = 65536 B
  double*       part1   = (double*)(ws + 65536);  // 4*16*33*8 = 16896 B
  double*       quadbuf = (double*)(ws + 82432);  // 4*4*64*8  = 8192 B
  unsigned int* cnt     = (unsigned int*)(ws + 90624);  // 16 B

  mmd_pass1<<<dim3(NPTS / 256, 4), 256, 0, stream>>>(src, tgt, sqArr, part1,
                                                     quadbuf, cnt);
  mmd_pass3<<<dim3(NPAIR3, 4), 256, 0, stream>>>(src, tgt, sqArr, part1,
                                                 quadbuf, cnt, out);
}

// Round 8
// 114.743 us; speedup vs baseline: 1.3648x; 1.0561x over previous
//
#include <hip/hip_runtime.h>
#include <hip/hip_bf16.h>

// MMD-RBF: B=4, Ns=Nt=2048 (N=4096 concat), K=32, KERNEL_MUL=2, KERNEL_NUM=5.
// Pass 1: per-point sq-norms + per-block partial {sum_sq, comp sums}; zero quadbuf+cnt
// Pass 3: 528 upper-tri 128x128 tile pairs per batch; Gram via MFMA bf16 hi/lo
//         split (4 products, fp32 accum), fragments loaded straight from global
//         (L2-resident); fused exp-ladder epilogue; kernel-symmetry doubling;
//         completion counter -> last block emits out[b]. No LDS tiles at all.

#define NPTS 4096   // per batch (2048 src + 2048 tgt)
#define HALF 2048
#define KDIM 32
#define T3   128    // tile dim
#define NTB3 32     // NPTS / T3
#define NPAIR3 528  // NTB3*(NTB3+1)/2
#define SPREAD 64

typedef __attribute__((ext_vector_type(8))) short short8v;  // 8 bf16 (4 VGPRs)
typedef __attribute__((ext_vector_type(4))) float f32x4;    // C/D frag

__device__ __forceinline__ float fast_exp2(float x) { return exp2f(x); }

__device__ __forceinline__ unsigned int bf16_rne(float x) {
  unsigned int u = __float_as_uint(x);
  return (u + 0x7fffu + ((u >> 16) & 1u)) >> 16;
}

__device__ __forceinline__ const float* point_ptr(const float* __restrict__ src,
                                                  const float* __restrict__ tgt,
                                                  int b, int p) {
  return (p < HALF) ? src + ((size_t)b * HALF + p) * KDIM
                    : tgt + ((size_t)b * HALF + (p - HALF)) * KDIM;
}

// build hi/lo bf16 fragments from 8 consecutive fp32 (lane's k-slice)
__device__ __forceinline__ void build_pair(const float4* __restrict__ p4,
                                           short8v& h, short8v& l) {
  const float4 v0 = p4[0], v1 = p4[1];
  const float xs[8] = {v0.x, v0.y, v0.z, v0.w, v1.x, v1.y, v1.z, v1.w};
#pragma unroll
  for (int e = 0; e < 8; ++e) {
    const float x = xs[e];
    const unsigned int hb = bf16_rne(x);
    const float hf = __uint_as_float(hb << 16);
    const unsigned int lb = bf16_rne(x - hf);
    h[e] = (short)hb;
    l[e] = (short)lb;
  }
}

// ---- Pass 1: sq per point; per-block partials -> part1; zero quadbuf+cnt ---
__global__ void mmd_pass1(const float* __restrict__ src, const float* __restrict__ tgt,
                          float* __restrict__ sqArr, double* __restrict__ part1,
                          double* __restrict__ quadbuf, unsigned int* __restrict__ cnt) {
  const int b = blockIdx.y;
  const int p = blockIdx.x * 256 + threadIdx.x;

  if (blockIdx.x == 0) {
    quadbuf[b * 4 * SPREAD + threadIdx.x] = 0.0;
    if (threadIdx.x == 0) cnt[b] = 0u;
  }

  const float* __restrict__ xp = point_ptr(src, tgt, b, p);
  float x[KDIM];
#pragma unroll
  for (int q = 0; q < 8; ++q) {
    float4 v = reinterpret_cast<const float4*>(xp)[q];
    x[4*q+0] = v.x; x[4*q+1] = v.y; x[4*q+2] = v.z; x[4*q+3] = v.w;
  }
  float s0 = 0.f, s1 = 0.f, s2 = 0.f, s3 = 0.f;
#pragma unroll
  for (int q = 0; q < 8; ++q) {
    s0 = fmaf(x[4*q+0], x[4*q+0], s0);
    s1 = fmaf(x[4*q+1], x[4*q+1], s1);
    s2 = fmaf(x[4*q+2], x[4*q+2], s2);
    s3 = fmaf(x[4*q+3], x[4*q+3], s3);
  }
  float sq = (s0 + s1) + (s2 + s3);
  sqArr[(size_t)b * NPTS + p] = sq;

  __shared__ float lx[256][KDIM + 1];
  __shared__ float part[8][KDIM];
  __shared__ float sqpart[4];

#pragma unroll
  for (int k = 0; k < KDIM; ++k) lx[threadIdx.x][k] = x[k];

  float w = sq;
#pragma unroll
  for (int off = 32; off > 0; off >>= 1) w += __shfl_down(w, off, 64);
  if ((threadIdx.x & 63) == 0) sqpart[threadIdx.x >> 6] = w;
  __syncthreads();

  const int k = threadIdx.x & 31, g = threadIdx.x >> 5;
  float ps = 0.f;
#pragma unroll 8
  for (int r = 0; r < 32; ++r) ps += lx[g * 32 + r][k];
  part[g][k] = ps;
  __syncthreads();

  double* slot = part1 + ((size_t)b * 16 + blockIdx.x) * 33;
  if (threadIdx.x < 32) {
    float tot = 0.f;
#pragma unroll
    for (int gg = 0; gg < 8; ++gg) tot += part[gg][threadIdx.x];
    slot[1 + threadIdx.x] = (double)tot;
  }
  if (threadIdx.x == 63)
    slot[0] = (double)(sqpart[0] + sqpart[1] + sqpart[2] + sqpart[3]);
}

// ---- Pass 3: MFMA Gram + fused epilogue, upper-tri, sym-doubled ------------
__global__ void __launch_bounds__(256, 4)
mmd_pass3(const float* __restrict__ src, const float* __restrict__ tgt,
          const float* __restrict__ sqArr, const double* __restrict__ part1,
          double* __restrict__ quadbuf, unsigned int* __restrict__ cnt,
          float* __restrict__ out) {
  const int t = blockIdx.x;            // 0..527 upper-tri pair index
  const int b = blockIdx.y;
  int by = (int)((sqrtf((float)(8 * t + 1)) - 1.0f) * 0.5f);
  while ((by + 1) * (by + 2) / 2 <= t) ++by;
  while (by * (by + 1) / 2 > t) --by;
  const int bx = t - by * (by + 1) / 2;

  const int tid = threadIdx.x;         // 256 = 4 waves
  const int lane = tid & 63;
  const int w = tid >> 6;
  const int lm = lane & 15;            // matrix index within 16
  const int lk = lane >> 4;            // k-group 0..3

  __shared__ double red[33];
  __shared__ float s_nc4;
  __shared__ double wsum[4];
  __shared__ unsigned int s_last;

  if (tid < 33) {
    double s = 0.0;
    for (int blk = 0; blk < 16; ++blk) s += part1[((size_t)b * 16 + blk) * 33 + tid];
    red[tid] = s;
  }
  __syncthreads();
  if (tid == 0) {
    double ssq = red[0], s2 = 0.0;
    for (int k = 1; k <= 32; ++k) s2 += red[k] * red[k];
    const double N = (double)NPTS;
    double bw = (2.0 * N * ssq - 2.0 * s2) / (N * N - N + 1e-8);
    bw *= 0.25;  // / KERNEL_MUL^(KERNEL_NUM//2)
    s_nc4 = (float)(-1.4426950408889634 / (bw * 16.0));  // widest bandwidth (t=4)
  }
  __syncthreads();
  const float nc4 = s_nc4;

  // wave region: 64x64 of the 128x128 tile
  const int rowbase = bx * T3 + (w & 1) * 64;
  const int colbase = by * T3 + (w >> 1) * 64;
  const float* __restrict__ sqA = sqArr + (size_t)b * NPTS;

  // cache B fragments (4 col-groups x hi/lo) + sq_j
  short8v Bh[4], Bl[4];
  float sqj[4];
#pragma unroll
  for (int cg = 0; cg < 4; ++cg) {
    const float* cp = point_ptr(src, tgt, b, colbase + cg * 16 + lm);
    build_pair(reinterpret_cast<const float4*>(cp) + lk * 2, Bh[cg], Bl[cg]);
    sqj[cg] = sqA[colbase + cg * 16 + lm];
  }

  double accd = 0.0;
#pragma unroll
  for (int rg = 0; rg < 4; ++rg) {
    short8v Ah, Al;
    const float* rp = point_ptr(src, tgt, b, rowbase + rg * 16 + lm);
    build_pair(reinterpret_cast<const float4*>(rp) + lk * 2, Ah, Al);
    // sq_i for this lane's 4 C-rows: row_local = lk*4 + reg
    const float4 sqi4 = *reinterpret_cast<const float4*>(sqA + rowbase + rg * 16 + lk * 4);
    const float sqi[4] = {sqi4.x, sqi4.y, sqi4.z, sqi4.w};
#pragma unroll
    for (int cg = 0; cg < 4; ++cg) {
      f32x4 acc = {0.f, 0.f, 0.f, 0.f};
      acc = __builtin_amdgcn_mfma_f32_16x16x32_bf16(Ah, Bh[cg], acc, 0, 0, 0);
      acc = __builtin_amdgcn_mfma_f32_16x16x32_bf16(Ah, Bl[cg], acc, 0, 0, 0);
      acc = __builtin_amdgcn_mfma_f32_16x16x32_bf16(Al, Bh[cg], acc, 0, 0, 0);
      acc = __builtin_amdgcn_mfma_f32_16x16x32_bf16(Al, Bl[cg], acc, 0, 0, 0);
      // epilogue: C lane map (verified m89): col = lane&15, row = lk*4 + reg
      float rs = 0.f;
#pragma unroll
      for (int reg = 0; reg < 4; ++reg) {
        const float L2 = fmaf(-2.0f, acc[reg], sqi[reg] + sqj[cg]);
        float e = fast_exp2(L2 * nc4);     // widest bandwidth
        float s = e;
        e *= e; s += e;                    // e3
        e *= e; s += e;                    // e2
        e *= e; s += e;                    // e1
        e *= e; s += e;                    // e0
        rs += s;
      }
      accd += (double)rs;
    }
  }

  // block reduce (4 waves) + spread atomics
#pragma unroll
  for (int off = 32; off > 0; off >>= 1) accd += __shfl_down(accd, off, 64);
  if ((tid & 63) == 0) wsum[tid >> 6] = accd;
  __syncthreads();
  if (tid == 0) {
    const double tot = wsum[0] + wsum[1] + wsum[2] + wsum[3];
    const int rh = (bx >= NTB3 / 2) ? 1 : 0;
    const int ch = (by >= NTB3 / 2) ? 1 : 0;
    const int q  = (rh << 1) | ch;
    const int qT = (ch << 1) | rh;
    const int slot = (bx + by * NTB3) & (SPREAD - 1);
    atomicAdd(&quadbuf[(((b << 2) | q) * SPREAD) + slot], tot);
    if (bx != by)
      atomicAdd(&quadbuf[(((b << 2) | qT) * SPREAD) + slot], tot);
    __threadfence();
    s_last = atomicAdd(&cnt[b], 1u);
  }
  __syncthreads();

  // last block of this batch combines the quadrants -> out[b]
  if (s_last == NPAIR3 - 1) {
    const int qq = tid >> 6, i = tid & 63;
    double v = atomicAdd(&quadbuf[((b << 2) | qq) * SPREAD + i], 0.0);
    double sv = (qq == 0 || qq == 3) ? v : -v;
#pragma unroll
    for (int off = 32; off > 0; off >>= 1) sv += __shfl_down(sv, off, 64);
    if ((tid & 63) == 0) wsum[tid >> 6] = sv;
    __syncthreads();
    if (tid == 0) {
      const double inv = 1.0 / ((double)HALF * (double)HALF);
      out[b] = (float)((wsum[0] + wsum[1] + wsum[2] + wsum[3]) * inv);
    }
  }
}

extern "C" void kernel_launch(void* const* d_in, const int* in_sizes, int n_in,
                              void* d_out, int out_size, void* d_ws, size_t ws_size,
                              hipStream_t stream) {
  const float* src = (const float*)d_in[0];
  const float* tgt = (const float*)d_in[1];
  float* out = (float*)d_out;

  char* ws = (char*)d_ws;
  float*        sqArr   = (float*)ws;             // 4*4096*4  = 65536 B
  double*       part1   = (double*)(ws + 65536);  // 4*16*33*8 = 16896 B
  double*       quadbuf = (double*)(ws + 82432);  // 4*4*64*8  = 8192 B
  unsigned int* cnt     = (unsigned int*)(ws + 90624);  // 16 B

  mmd_pass1<<<dim3(NPTS / 256, 4), 256, 0, stream>>>(src, tgt, sqArr, part1,
                                                     quadbuf, cnt);
  mmd_pass3<<<dim3(NPAIR3, 4), 256, 0, stream>>>(src, tgt, sqArr, part1,
                                                 quadbuf, cnt, out);
}